// Round 16
// baseline (294.091 us; speedup 1.0000x reference)
//
#include <hip/hip_runtime.h>

#define NS 64
#define HH 64
#define WW 64
#define VD 64
#define VH 64
#define VW 64
#define NVOX (VD*VH*VW)
#define NPIX (NS*HH*WW)
#define RES 1.5f
#define NTAB (NS*27)
#define WIN 6
#define SPLIT 8
#define COL_PAD 67
#define GP_ROW 68
#define GP_SLC (66*GP_ROW)      // 4488 floats per padded slice
#define GP_TOT (NS*GP_SLC)      // 287232
#define BAND 16                 // staged g-rows per slice (actual need <=12 for this data)

// ---------------------------------------------------------------
// table entry (16 floats):
//  [0..3]  a,c,b,d   (ws = a*rx + b*ry, hs = c*rx + d*ry)
//  [4..7]  Ux,Uy,Vx,Vy
//  [8..11] Uz,Vz,Cx,Cy
//  [12..15]Cz,psf_k,0,0
// ---------------------------------------------------------------
__global__ __launch_bounds__(256) void k_setup(const float* __restrict__ tr,
                                               const float* __restrict__ psf,
                                               float* __restrict__ tab) {
    int i = blockIdx.x * 256 + threadIdx.x;
    if (i >= NTAB) return;
    int s = i / 27, k = i % 27;
    const float* p = tr + s * 12;
    float R00 = p[0], R01 = p[1], R02 = p[2],  t0 = p[3];
    float R10 = p[4], R11 = p[5], R12 = p[6],  t1 = p[7];
    float R20 = p[8], R21 = p[9], R22 = p[10], t2 = p[11];
    float Ux = RES * R00, Uy = RES * R10, Uz = RES * R20;
    float Vx = RES * R01, Vy = RES * R11, Vz = RES * R21;
    float ox = (float)(k % 3 - 1), oy = (float)((k / 3) % 3 - 1), oz = (float)(k / 9 - 1);
    float Cx = t0 + 31.5f + R00 * ox + R01 * oy + R02 * oz - 31.5f * (Ux + Vx);
    float Cy = t1 + 31.5f + R10 * ox + R11 * oy + R12 * oz - 31.5f * (Uy + Vy);
    float Cz = t2 + 31.5f + R20 * ox + R21 * oy + R22 * oz - 31.5f * (Uz + Vz);
    float inv = 1.f / (Ux * Vy - Uy * Vx);
    float* e = tab + i * 16;
    e[0] = Vy * inv;  e[1] = -Uy * inv;  e[2] = -Vx * inv; e[3] = Ux * inv;
    e[4] = Ux; e[5] = Uy; e[6] = Vx; e[7] = Vy;
    e[8] = Uz; e[9] = Vz; e[10] = Cx; e[11] = Cy;
    e[12] = Cz; e[13] = psf[k]; e[14] = 0.f; e[15] = 0.f;
}

// ---------------------------------------------------------------
// Branch-free trilinear gather (clamped idx, zeroed weights).
// ---------------------------------------------------------------
__device__ __forceinline__ float trilin_gather_bf(const float* __restrict__ vol,
                                                  float px, float py, float pz) {
    float x0 = floorf(px), y0 = floorf(py), z0 = floorf(pz);
    float fx = px - x0, fy = py - y0, fz = pz - z0;
    int ix = (int)x0, iy = (int)y0, iz = (int)z0;

    float wx0 = ((unsigned)ix       < 64u) ? (1.f - fx) : 0.f;
    float wx1 = ((unsigned)(ix + 1) < 64u) ? fx         : 0.f;
    float wy0 = ((unsigned)iy       < 64u) ? (1.f - fy) : 0.f;
    float wy1 = ((unsigned)(iy + 1) < 64u) ? fy         : 0.f;
    float wz0 = ((unsigned)iz       < 64u) ? (1.f - fz) : 0.f;
    float wz1 = ((unsigned)(iz + 1) < 64u) ? fz         : 0.f;

    int xc0 = min(max(ix, 0), 63),     xc1 = min(max(ix + 1, 0), 63);
    int yc0 = min(max(iy, 0), 63) << 6,  yc1 = min(max(iy + 1, 0), 63) << 6;
    int zc0 = min(max(iz, 0), 63) << 12, zc1 = min(max(iz + 1, 0), 63) << 12;

    float v000 = vol[zc0 + yc0 + xc0], v001 = vol[zc0 + yc0 + xc1];
    float v010 = vol[zc0 + yc1 + xc0], v011 = vol[zc0 + yc1 + xc1];
    float v100 = vol[zc1 + yc0 + xc0], v101 = vol[zc1 + yc0 + xc1];
    float v110 = vol[zc1 + yc1 + xc0], v111 = vol[zc1 + yc1 + xc1];

    float w00 = wx0 * wy0, w01 = wx1 * wy0, w10 = wx0 * wy1, w11 = wx1 * wy1;
    float lo = fmaf(w00, v000, fmaf(w01, v001, fmaf(w10, v010, w11 * v011)));
    float hi = fmaf(w00, v100, fmaf(w01, v101, fmaf(w10, v110, w11 * v111)));
    return fmaf(wz0, lo, wz1 * hi);
}

// ---------------------------------------------------------------
// Forward projection A: 1 thread per pixel, per-tap OOB skip.
// Output into ZERO-PADDED g. SUB: g = slc - A(vin).
// ---------------------------------------------------------------
template<bool SUB>
__global__ __launch_bounds__(256) void k_a(const float* __restrict__ vin,
                                           float* __restrict__ gp,
                                           const float* __restrict__ tr,
                                           const float* __restrict__ psf,
                                           const float* __restrict__ slc) {
    __shared__ float s_psf[27];
    if (threadIdx.x < 27) s_psf[threadIdx.x] = psf[threadIdx.x];
    __syncthreads();
    int gid = blockIdx.x * 256 + threadIdx.x;
    int s = gid >> 12;
    int h = (gid >> 6) & 63, w = gid & 63;
    const float* p = tr + s * 12;
    float R0 = p[0], R1 = p[1], R2 = p[2],  t0 = p[3];
    float R3 = p[4], R4 = p[5], R5 = p[6],  t1 = p[7];
    float R6 = p[8], R7 = p[9], R8 = p[10], t2 = p[11];
    float xs = ((float)w - 31.5f) * RES;
    float ys = ((float)h - 31.5f) * RES;
    float p0x = fmaf(R0, xs, fmaf(R1, ys, t0)) + 31.5f;
    float p0y = fmaf(R3, xs, fmaf(R4, ys, t1)) + 31.5f;
    float p0z = fmaf(R6, xs, fmaf(R7, ys, t2)) + 31.5f;
    float a = 0.f;
#pragma unroll
    for (int k = 0; k < 27; ++k) {
        const float ox = (float)(k % 3 - 1), oy = (float)((k / 3) % 3 - 1), oz = (float)(k / 9 - 1);
        float px = p0x + ox * R0 + oy * R1 + oz * R2;
        float py = p0y + ox * R3 + oy * R4 + oz * R5;
        float pz = p0z + ox * R6 + oy * R7 + oz * R8;
        bool inb = (px > -1.f) & (px < 64.f) & (py > -1.f) & (py < 64.f)
                 & (pz > -1.f) & (pz < 64.f);
        if (inb) a = fmaf(s_psf[k], trilin_gather_bf(vin, px, py, pz), a);
    }
    float outv = SUB ? (slc[gid] - a) : a;
    gp[s * GP_SLC + (h + 1) * GP_ROW + (w + 1)] = outv;
}

// ---------------- block reduce helpers (256-thr kernels) ----------------
__device__ __forceinline__ void bred256(float v, float* dst) {
#pragma unroll
    for (int off = 32; off > 0; off >>= 1) v += __shfl_down(v, off, 64);
    __shared__ float s_red[4];
    int lane = threadIdx.x & 63, wid = threadIdx.x >> 6;
    if (lane == 0) s_red[wid] = v;
    __syncthreads();
    if (threadIdx.x == 0) atomicAdd(dst, s_red[0] + s_red[1] + s_red[2] + s_red[3]);
}

__device__ __forceinline__ void bred2(float a, float b, float* da, float* db) {
#pragma unroll
    for (int off = 32; off > 0; off >>= 1) {
        a += __shfl_down(a, off, 64);
        b += __shfl_down(b, off, 64);
    }
    __shared__ float s_red[8];
    int lane = threadIdx.x & 63, wid = threadIdx.x >> 6;
    if (lane == 0) { s_red[wid] = a; s_red[4 + wid] = b; }
    __syncthreads();
    if (threadIdx.x == 0) {
        atomicAdd(da, (s_red[0] + s_red[1]) + (s_red[2] + s_red[3]));
        atomicAdd(db, (s_red[4] + s_red[5]) + (s_red[6] + s_red[7]));
    }
}

// ---------------------------------------------------------------
// Adjoint At: wave-uniform slice; g rows STAGED IN LDS (16-row
// band per slice, computed exactly per wave from the 27 taps'
// linear hs(X) endpoints). 6-slot register z-window, 6-atomic
// epilogue flush (atomics kept OUT of the inner loop — r12/r13
// measured ~200 cy/wave-op for in-loop LDS atomics).
// Block = 512 thr = 8 waves; wave = 64 cols (one y-row) x 1 slice.
// blockIdx: Yb = b>>3, split = b&7; slice = split*8 + wave.
// ---------------------------------------------------------------
__global__ __launch_bounds__(512, 2) void k_atv(const float* __restrict__ g,
                                                float* __restrict__ part,
                                                const float* __restrict__ tab) {
    __shared__ float cols[64][COL_PAD];          // 17.2 KB
    __shared__ float sgb[8][BAND * GP_ROW];      // 34.8 KB
    int tid = threadIdx.x;
    {
        float4* c4 = (float4*)&cols[0][0];       // 64*67 = 4288 floats = 1072 f4
#pragma unroll
        for (int i = 0; i < 3; ++i) {
            int j = tid + i * 512;
            if (j < 1072) c4[j] = make_float4(0.f, 0.f, 0.f, 0.f);
        }
    }

    int Yb    = blockIdx.x >> 3;
    int split = blockIdx.x & 7;
    int lane  = tid & 63;               // col x
    int wave  = tid >> 6;               // 0..7
    int s = __builtin_amdgcn_readfirstlane(split * 8 + wave);  // wave-uniform
    float X = (float)lane, Y = (float)Yb;

    const float* tb = tab + s * 27 * 16;

    // --- per-wave h band: hs(X) linear -> exact min/max from endpoints ---
    float hlo = 1e9f, hhi = -1e9f;
    if (lane < 27) {
        const float* e = tb + lane * 16;
        float c = e[1], d = e[3], Cx = e[10], Cy = e[11];
        float ryd = d * (Y - Cy);
        float hs0 = c * (0.f  - Cx) + ryd;
        float hs1 = c * (63.f - Cx) + ryd;
        hlo = fminf(hs0, hs1);
        hhi = fmaxf(hs0, hs1);
    }
#pragma unroll
    for (int off = 32; off > 0; off >>= 1) {
        hlo = fminf(hlo, __shfl_xor(hlo, off, 64));
        hhi = fmaxf(hhi, __shfl_xor(hhi, off, 64));
    }
    int rlo = (int)__builtin_amdgcn_fmed3f(floorf(hlo), -1.f, 63.f) + 1; // min padded row
    int hbase = min(rlo, 66 - BAND);                                      // rlo >= 0

    // --- stage BAND contiguous padded rows of this slice (coalesced f4) ---
    {
        const float4* gs4 = (const float4*)(g + s * GP_SLC + hbase * GP_ROW);
        float4* sd4 = (float4*)&sgb[wave][0];    // BAND*68/4 = 272 f4
#pragma unroll
        for (int i = 0; i < 5; ++i) {
            int j = lane + i * 64;
            if (j < 272) sd4[j] = gs4[j];
        }
    }
    __syncthreads();

    // window base from center tap (k=13)
    const float* ec = tb + 13 * 16;
    float4 ce0 = *(const float4*)(ec);
    float4 ce2 = *(const float4*)(ec + 8);
    float4 ce3 = *(const float4*)(ec + 12);
    float rxc = X - ce2.z, ryc = Y - ce2.w;
    float wsc = ce0.x * rxc + ce0.z * ryc;
    float hsc = ce0.y * rxc + ce0.w * ryc;
    float pzc = fmaf(wsc, ce2.x, fmaf(hsc, ce2.y, ce3.x));
    float basef = floorf(pzc) - 2.f;
    int   basei = (int)basef;

    float acc[WIN];
#pragma unroll
    for (int j = 0; j < WIN; ++j) acc[j] = 0.f;

#pragma unroll 3
    for (int k = 0; k < 27; ++k) {
        const float* e = tb + k * 16;
        float4 e0 = *(const float4*)(e);
        float4 e1 = *(const float4*)(e + 4);
        float4 e2 = *(const float4*)(e + 8);
        float4 e3 = *(const float4*)(e + 12);
        float rx = X - e2.z, ry = Y - e2.w;        // X - Cx, Y - Cy
        float ws = e0.x * rx + e0.z * ry;
        float hs = e0.y * rx + e0.w * ry;
        float w0f = __builtin_amdgcn_fmed3f(floorf(ws), -1.f, 63.f);
        float h0f = __builtin_amdgcn_fmed3f(floorf(hs), -1.f, 63.f);
        int wA = (int)w0f, hA = (int)h0f;
        float Ux = e1.x, Uy = e1.y, Vx = e1.z, Vy = e1.w;
        float Uz = e2.x, Vz = e2.y;
        float Czb = e3.x - basef;
        float psfk = e3.y;
        float Cxr = -rx, Cyr = -ry;                // C - voxel(x,y)
        int hrel = hA + 1 - hbase;                 // in [0, BAND-2]
        int colb = wA + 1;
#pragma unroll
        for (int dh = 0; dh < 2; ++dh) {
            float fh = h0f + (float)dh;
            float tx  = fmaf(fh, Vx, Cxr);
            float ty  = fmaf(fh, Vy, Cyr);
            float tzb = fmaf(fh, Vz, Czb);
            int rowoff = (hrel + dh) * GP_ROW + colb;
#pragma unroll
            for (int dw = 0; dw < 2; ++dw) {
                float fw = w0f + (float)dw;
                float ddx = fmaf(fw, Ux, tx);      // px - X
                float ddy = fmaf(fw, Uy, ty);      // py - Y
                float wx = fmaxf(1.f - fabsf(ddx), 0.f);
                float wy = fmaxf(1.f - fabsf(ddy), 0.f);
                float gv = sgb[wave][rowoff + dw]; // staged; OOB pad -> 0
                float val = wx * wy * psfk * gv;
                float prel = fmaf(fw, Uz, tzb);    // pz - basef
#pragma unroll
                for (int j = 0; j < WIN; ++j) {
                    float t = fmaxf(0.f, 1.f - fabsf(prel - (float)j));
                    acc[j] = fmaf(val, t, acc[j]);
                }
            }
        }
    }

#pragma unroll
    for (int j = 0; j < WIN; ++j) {
        int zj = basei + j;
        int okz = ((unsigned)zj < 64u);
        int zc = min(max(zj, 0), 63);
        atomicAdd(&cols[lane][zc], okz ? acc[j] : 0.f);
    }
    __syncthreads();

    // write partial: full y-row, 64 cols x 64 z
    float* pout = part + split * NVOX + (Yb << 6);
#pragma unroll
    for (int i = 0; i < 8; ++i) {
        int j = tid + i * 512;
        int z = j >> 6, x = j & 63;
        pout[(z << 12) + x] = cols[x][z];
    }
}

// ---------------- s-step CG consumers ----------------
// scal: [0]=rr0 [1]=r0.K1 [2]=K1.K1 [3]=r0.K2 [4]=K1.K2

__device__ __forceinline__ float sum8(const float* __restrict__ part, int i) {
    float a = 0.f;
#pragma unroll
    for (int j = 0; j < SPLIT; ++j) a += part[j * NVOX + i];
    return a;
}

// r0 = sum8(part); rr0
__global__ __launch_bounds__(256) void k_r0(const float* __restrict__ part,
                                            float* __restrict__ r0,
                                            float* __restrict__ scal) {
    int i = blockIdx.x * 256 + threadIdx.x;
    float rv = sum8(part, i);
    r0[i] = rv;
    bred256(rv * rv, &scal[0]);
}

// K1 = sum8(part); r0.K1, K1.K1
__global__ __launch_bounds__(256) void k_k1(const float* __restrict__ part,
                                            const float* __restrict__ r0,
                                            float* __restrict__ K1,
                                            float* __restrict__ scal) {
    int i = blockIdx.x * 256 + threadIdx.x;
    float apv = sum8(part, i);
    K1[i] = apv;
    bred2(r0[i] * apv, apv * apv, &scal[1], &scal[2]);
}

// r0.K2, K1.K2   (K2 itself never stored)
__global__ __launch_bounds__(256) void k_dots2(const float* __restrict__ part,
                                               const float* __restrict__ r0,
                                               const float* __restrict__ K1,
                                               float* __restrict__ scal) {
    int i = blockIdx.x * 256 + threadIdx.x;
    float apv = sum8(part, i);
    bred2(r0[i] * apv, K1[i] * apv, &scal[3], &scal[4]);
}

// out = relu(x0 + c1 r0 + c2 K1), coefficients from the 5 scalars
__global__ __launch_bounds__(256) void k_out(const float* __restrict__ x0,
                                             const float* __restrict__ r0,
                                             const float* __restrict__ K1,
                                             const float* __restrict__ scal,
                                             float* __restrict__ out) {
    int i = blockIdx.x * 256 + threadIdx.x;
    float rr0  = scal[0], rK1 = scal[1], K1K1 = scal[2];
    float rK2  = scal[3], K1K2 = scal[4];
    float a0   = rr0 / rK1;                                   // alpha0 (pAp0 = r0.K1)
    float rr1  = rr0 - 2.f * a0 * rK1 + a0 * a0 * K1K1;       // |r1|^2
    float beta = rr1 / rr0;
    float ob   = 1.f + beta;
    // pAp1 = (ob r0 - a0 K1) . (ob K1 - a0 K2)
    float pAp1 = ob * ob * rK1 - ob * a0 * rK2 - a0 * ob * K1K1 + a0 * a0 * K1K2;
    float a1   = rr1 / pAp1;
    float c1   = a0 + a1 * ob;
    float c2   = -a1 * a0;
    float v = fmaf(c2, K1[i], fmaf(c1, r0[i], x0[i]));
    out[i] = v > 0.f ? v : 0.f;
}

extern "C" void kernel_launch(void* const* d_in, const int* in_sizes, int n_in,
                              void* d_out, int out_size, void* d_ws, size_t ws_size,
                              hipStream_t stream) {
    const float* transforms = (const float*)d_in[0];
    const float* slices     = (const float*)d_in[1];
    const float* volume     = (const float*)d_in[2];
    const float* psf        = (const float*)d_in[3];
    float* out = (float*)d_out;

    float* tab    = (float*)d_ws;             // NTAB*16
    float* gbuf   = tab    + NTAB * 16;       // GP_TOT (zero-padded g)
    float* scal   = gbuf   + GP_TOT;          // 8 floats
    float* part   = scal   + 8;               // 8 * NVOX
    float* r0     = part   + SPLIT * NVOX;
    float* K1     = r0     + NVOX;

    const int ablk = 64 * SPLIT;              // 512 (k_atv)
    const int fblk = NPIX / 256;              // 1024 (k_a)
    const int vblk = NVOX / 256;              // 1024

    // one memset covers padded-g borders AND scal
    hipMemsetAsync(gbuf, 0, (GP_TOT + 8) * sizeof(float), stream);
    k_setup<<<(NTAB + 255) / 256, 256, 0, stream>>>(transforms, psf, tab);

    // r0 = At(slices - A(x0)); rr0
    k_a<true><<<fblk, 256, 0, stream>>>(volume, gbuf, transforms, psf, slices);
    k_atv<<<ablk, 512, 0, stream>>>(gbuf, part, tab);
    k_r0<<<vblk, 256, 0, stream>>>(part, r0, scal);

    // K1 = AtA(r0); r0.K1, K1.K1
    k_a<false><<<fblk, 256, 0, stream>>>(r0, gbuf, transforms, psf, nullptr);
    k_atv<<<ablk, 512, 0, stream>>>(gbuf, part, tab);
    k_k1<<<vblk, 256, 0, stream>>>(part, r0, K1, scal);

    // K2 = AtA(K1); r0.K2, K1.K2 (K2 not stored)
    k_a<false><<<fblk, 256, 0, stream>>>(K1, gbuf, transforms, psf, nullptr);
    k_atv<<<ablk, 512, 0, stream>>>(gbuf, part, tab);
    k_dots2<<<vblk, 256, 0, stream>>>(part, r0, K1, scal);

    // out = relu(x0 + c1 r0 + c2 K1)
    k_out<<<vblk, 256, 0, stream>>>(volume, r0, K1, scal, out);
}

// Round 17
// 293.273 us; speedup vs baseline: 1.0028x; 1.0028x over previous
//
#include <hip/hip_runtime.h>

#define NS 64
#define HH 64
#define WW 64
#define VD 64
#define VH 64
#define VW 64
#define NVOX (VD*VH*VW)
#define NPIX (NS*HH*WW)
#define RES 1.5f
#define NTAB (NS*27)
#define WIN 6
#define SPLIT 8
#define COL_PAD 67
#define GP_ROW 68
#define GP_SLC (66*GP_ROW)      // 4488 floats per padded slice
#define GP_TOT (NS*GP_SLC)      // 287232
#define BAND 16                 // staged g-rows per slice (actual need <=12 for this data)

// ---------------------------------------------------------------
// table entry (16 floats):
//  [0..3]  a,c,b,d   (ws = a*rx + b*ry, hs = c*rx + d*ry)
//  [4..7]  Ux,Uy,Vx,Vy
//  [8..11] Uz,Vz,Cx,Cy
//  [12..15]Cz,psf_k,0,0
// ---------------------------------------------------------------
__global__ __launch_bounds__(256) void k_setup(const float* __restrict__ tr,
                                               const float* __restrict__ psf,
                                               float* __restrict__ tab) {
    int i = blockIdx.x * 256 + threadIdx.x;
    if (i >= NTAB) return;
    int s = i / 27, k = i % 27;
    const float* p = tr + s * 12;
    float R00 = p[0], R01 = p[1], R02 = p[2],  t0 = p[3];
    float R10 = p[4], R11 = p[5], R12 = p[6],  t1 = p[7];
    float R20 = p[8], R21 = p[9], R22 = p[10], t2 = p[11];
    float Ux = RES * R00, Uy = RES * R10, Uz = RES * R20;
    float Vx = RES * R01, Vy = RES * R11, Vz = RES * R21;
    float ox = (float)(k % 3 - 1), oy = (float)((k / 3) % 3 - 1), oz = (float)(k / 9 - 1);
    float Cx = t0 + 31.5f + R00 * ox + R01 * oy + R02 * oz - 31.5f * (Ux + Vx);
    float Cy = t1 + 31.5f + R10 * ox + R11 * oy + R12 * oz - 31.5f * (Uy + Vy);
    float Cz = t2 + 31.5f + R20 * ox + R21 * oy + R22 * oz - 31.5f * (Uz + Vz);
    float inv = 1.f / (Ux * Vy - Uy * Vx);
    float* e = tab + i * 16;
    e[0] = Vy * inv;  e[1] = -Uy * inv;  e[2] = -Vx * inv; e[3] = Ux * inv;
    e[4] = Ux; e[5] = Uy; e[6] = Vx; e[7] = Vy;
    e[8] = Uz; e[9] = Vz; e[10] = Cx; e[11] = Cy;
    e[12] = Cz; e[13] = psf[k]; e[14] = 0.f; e[15] = 0.f;
}

// ---------------------------------------------------------------
// Branch-free trilinear gather (clamped idx, zeroed weights).
// ---------------------------------------------------------------
__device__ __forceinline__ float trilin_gather_bf(const float* __restrict__ vol,
                                                  float px, float py, float pz) {
    float x0 = floorf(px), y0 = floorf(py), z0 = floorf(pz);
    float fx = px - x0, fy = py - y0, fz = pz - z0;
    int ix = (int)x0, iy = (int)y0, iz = (int)z0;

    float wx0 = ((unsigned)ix       < 64u) ? (1.f - fx) : 0.f;
    float wx1 = ((unsigned)(ix + 1) < 64u) ? fx         : 0.f;
    float wy0 = ((unsigned)iy       < 64u) ? (1.f - fy) : 0.f;
    float wy1 = ((unsigned)(iy + 1) < 64u) ? fy         : 0.f;
    float wz0 = ((unsigned)iz       < 64u) ? (1.f - fz) : 0.f;
    float wz1 = ((unsigned)(iz + 1) < 64u) ? fz         : 0.f;

    int xc0 = min(max(ix, 0), 63),     xc1 = min(max(ix + 1, 0), 63);
    int yc0 = min(max(iy, 0), 63) << 6,  yc1 = min(max(iy + 1, 0), 63) << 6;
    int zc0 = min(max(iz, 0), 63) << 12, zc1 = min(max(iz + 1, 0), 63) << 12;

    float v000 = vol[zc0 + yc0 + xc0], v001 = vol[zc0 + yc0 + xc1];
    float v010 = vol[zc0 + yc1 + xc0], v011 = vol[zc0 + yc1 + xc1];
    float v100 = vol[zc1 + yc0 + xc0], v101 = vol[zc1 + yc0 + xc1];
    float v110 = vol[zc1 + yc1 + xc0], v111 = vol[zc1 + yc1 + xc1];

    float w00 = wx0 * wy0, w01 = wx1 * wy0, w10 = wx0 * wy1, w11 = wx1 * wy1;
    float lo = fmaf(w00, v000, fmaf(w01, v001, fmaf(w10, v010, w11 * v011)));
    float hi = fmaf(w00, v100, fmaf(w01, v101, fmaf(w10, v110, w11 * v111)));
    return fmaf(wz0, lo, wz1 * hi);
}

// ---------------------------------------------------------------
// Forward projection A: 1 thread per pixel, per-tap OOB skip.
// Output into ZERO-PADDED g. SUB: g = slc - A(vin).
// ---------------------------------------------------------------
template<bool SUB>
__global__ __launch_bounds__(256) void k_a(const float* __restrict__ vin,
                                           float* __restrict__ gp,
                                           const float* __restrict__ tr,
                                           const float* __restrict__ psf,
                                           const float* __restrict__ slc) {
    __shared__ float s_psf[27];
    if (threadIdx.x < 27) s_psf[threadIdx.x] = psf[threadIdx.x];
    __syncthreads();
    int gid = blockIdx.x * 256 + threadIdx.x;
    int s = gid >> 12;
    int h = (gid >> 6) & 63, w = gid & 63;
    const float* p = tr + s * 12;
    float R0 = p[0], R1 = p[1], R2 = p[2],  t0 = p[3];
    float R3 = p[4], R4 = p[5], R5 = p[6],  t1 = p[7];
    float R6 = p[8], R7 = p[9], R8 = p[10], t2 = p[11];
    float xs = ((float)w - 31.5f) * RES;
    float ys = ((float)h - 31.5f) * RES;
    float p0x = fmaf(R0, xs, fmaf(R1, ys, t0)) + 31.5f;
    float p0y = fmaf(R3, xs, fmaf(R4, ys, t1)) + 31.5f;
    float p0z = fmaf(R6, xs, fmaf(R7, ys, t2)) + 31.5f;
    float a = 0.f;
#pragma unroll
    for (int k = 0; k < 27; ++k) {
        const float ox = (float)(k % 3 - 1), oy = (float)((k / 3) % 3 - 1), oz = (float)(k / 9 - 1);
        float px = p0x + ox * R0 + oy * R1 + oz * R2;
        float py = p0y + ox * R3 + oy * R4 + oz * R5;
        float pz = p0z + ox * R6 + oy * R7 + oz * R8;
        bool inb = (px > -1.f) & (px < 64.f) & (py > -1.f) & (py < 64.f)
                 & (pz > -1.f) & (pz < 64.f);
        if (inb) a = fmaf(s_psf[k], trilin_gather_bf(vin, px, py, pz), a);
    }
    float outv = SUB ? (slc[gid] - a) : a;
    gp[s * GP_SLC + (h + 1) * GP_ROW + (w + 1)] = outv;
}

// ---------------- block reduce helpers (256-thr kernels) ----------------
__device__ __forceinline__ void bred256(float v, float* dst) {
#pragma unroll
    for (int off = 32; off > 0; off >>= 1) v += __shfl_down(v, off, 64);
    __shared__ float s_red[4];
    int lane = threadIdx.x & 63, wid = threadIdx.x >> 6;
    if (lane == 0) s_red[wid] = v;
    __syncthreads();
    if (threadIdx.x == 0) atomicAdd(dst, s_red[0] + s_red[1] + s_red[2] + s_red[3]);
}

__device__ __forceinline__ void bred2(float a, float b, float* da, float* db) {
#pragma unroll
    for (int off = 32; off > 0; off >>= 1) {
        a += __shfl_down(a, off, 64);
        b += __shfl_down(b, off, 64);
    }
    __shared__ float s_red[8];
    int lane = threadIdx.x & 63, wid = threadIdx.x >> 6;
    if (lane == 0) { s_red[wid] = a; s_red[4 + wid] = b; }
    __syncthreads();
    if (threadIdx.x == 0) {
        atomicAdd(da, (s_red[0] + s_red[1]) + (s_red[2] + s_red[3]));
        atomicAdd(db, (s_red[4] + s_red[5]) + (s_red[6] + s_red[7]));
    }
}

// ---------------------------------------------------------------
// Adjoint At: wave-uniform slice; g rows STAGED IN LDS (16-row
// band per slice, computed exactly per wave from the 27 taps'
// linear hs(X) endpoints). 6-slot register z-window, 6-atomic
// epilogue flush (atomics kept OUT of the inner loop — r12/r13
// measured ~200 cy/wave-op for in-loop LDS atomics).
// Block = 512 thr = 8 waves; wave = 64 cols (one y-row) x 1 slice.
// blockIdx: Yb = b>>3, split = b&7; slice = split*8 + wave.
// ---------------------------------------------------------------
__global__ __launch_bounds__(512, 2) void k_atv(const float* __restrict__ g,
                                                float* __restrict__ part,
                                                const float* __restrict__ tab) {
    __shared__ float cols[64][COL_PAD];          // 17.2 KB
    __shared__ float sgb[8][BAND * GP_ROW];      // 34.8 KB
    int tid = threadIdx.x;
    {
        float4* c4 = (float4*)&cols[0][0];       // 64*67 = 4288 floats = 1072 f4
#pragma unroll
        for (int i = 0; i < 3; ++i) {
            int j = tid + i * 512;
            if (j < 1072) c4[j] = make_float4(0.f, 0.f, 0.f, 0.f);
        }
    }

    int Yb    = blockIdx.x >> 3;
    int split = blockIdx.x & 7;
    int lane  = tid & 63;               // col x
    int wave  = tid >> 6;               // 0..7
    int s = __builtin_amdgcn_readfirstlane(split * 8 + wave);  // wave-uniform
    float X = (float)lane, Y = (float)Yb;

    const float* tb = tab + s * 27 * 16;

    // --- per-wave h band: hs(X) linear -> exact min/max from endpoints ---
    float hlo = 1e9f, hhi = -1e9f;
    if (lane < 27) {
        const float* e = tb + lane * 16;
        float c = e[1], d = e[3], Cx = e[10], Cy = e[11];
        float ryd = d * (Y - Cy);
        float hs0 = c * (0.f  - Cx) + ryd;
        float hs1 = c * (63.f - Cx) + ryd;
        hlo = fminf(hs0, hs1);
        hhi = fmaxf(hs0, hs1);
    }
#pragma unroll
    for (int off = 32; off > 0; off >>= 1) {
        hlo = fminf(hlo, __shfl_xor(hlo, off, 64));
        hhi = fmaxf(hhi, __shfl_xor(hhi, off, 64));
    }
    int rlo = (int)__builtin_amdgcn_fmed3f(floorf(hlo), -1.f, 63.f) + 1; // min padded row
    int hbase = min(rlo, 66 - BAND);                                      // rlo >= 0

    // --- stage BAND contiguous padded rows of this slice (coalesced f4) ---
    {
        const float4* gs4 = (const float4*)(g + s * GP_SLC + hbase * GP_ROW);
        float4* sd4 = (float4*)&sgb[wave][0];    // BAND*68/4 = 272 f4
#pragma unroll
        for (int i = 0; i < 5; ++i) {
            int j = lane + i * 64;
            if (j < 272) sd4[j] = gs4[j];
        }
    }
    __syncthreads();

    // window base from center tap (k=13)
    const float* ec = tb + 13 * 16;
    float4 ce0 = *(const float4*)(ec);
    float4 ce2 = *(const float4*)(ec + 8);
    float4 ce3 = *(const float4*)(ec + 12);
    float rxc = X - ce2.z, ryc = Y - ce2.w;
    float wsc = ce0.x * rxc + ce0.z * ryc;
    float hsc = ce0.y * rxc + ce0.w * ryc;
    float pzc = fmaf(wsc, ce2.x, fmaf(hsc, ce2.y, ce3.x));
    float basef = floorf(pzc) - 2.f;
    int   basei = (int)basef;

    float acc[WIN];
#pragma unroll
    for (int j = 0; j < WIN; ++j) acc[j] = 0.f;

#pragma unroll 3
    for (int k = 0; k < 27; ++k) {
        const float* e = tb + k * 16;
        float4 e0 = *(const float4*)(e);
        float4 e1 = *(const float4*)(e + 4);
        float4 e2 = *(const float4*)(e + 8);
        float4 e3 = *(const float4*)(e + 12);
        float rx = X - e2.z, ry = Y - e2.w;        // X - Cx, Y - Cy
        float ws = e0.x * rx + e0.z * ry;
        float hs = e0.y * rx + e0.w * ry;
        float w0f = __builtin_amdgcn_fmed3f(floorf(ws), -1.f, 63.f);
        float h0f = __builtin_amdgcn_fmed3f(floorf(hs), -1.f, 63.f);
        int wA = (int)w0f, hA = (int)h0f;
        float Ux = e1.x, Uy = e1.y, Vx = e1.z, Vy = e1.w;
        float Uz = e2.x, Vz = e2.y;
        float Czb = e3.x - basef;
        float psfk = e3.y;
        float Cxr = -rx, Cyr = -ry;                // C - voxel(x,y)
        int hrel = hA + 1 - hbase;                 // in [0, BAND-2]
        int colb = wA + 1;
#pragma unroll
        for (int dh = 0; dh < 2; ++dh) {
            float fh = h0f + (float)dh;
            float tx  = fmaf(fh, Vx, Cxr);
            float ty  = fmaf(fh, Vy, Cyr);
            float tzb = fmaf(fh, Vz, Czb);
            int rowoff = (hrel + dh) * GP_ROW + colb;
#pragma unroll
            for (int dw = 0; dw < 2; ++dw) {
                float fw = w0f + (float)dw;
                float ddx = fmaf(fw, Ux, tx);      // px - X
                float ddy = fmaf(fw, Uy, ty);      // py - Y
                float wx = fmaxf(1.f - fabsf(ddx), 0.f);
                float wy = fmaxf(1.f - fabsf(ddy), 0.f);
                float gv = sgb[wave][rowoff + dw]; // staged; OOB pad -> 0
                float val = wx * wy * psfk * gv;
                float prel = fmaf(fw, Uz, tzb);    // pz - basef
#pragma unroll
                for (int j = 0; j < WIN; ++j) {
                    float t = fmaxf(0.f, 1.f - fabsf(prel - (float)j));
                    acc[j] = fmaf(val, t, acc[j]);
                }
            }
        }
    }

#pragma unroll
    for (int j = 0; j < WIN; ++j) {
        int zj = basei + j;
        int okz = ((unsigned)zj < 64u);
        int zc = min(max(zj, 0), 63);
        atomicAdd(&cols[lane][zc], okz ? acc[j] : 0.f);
    }
    __syncthreads();

    // write partial: full y-row, 64 cols x 64 z
    float* pout = part + split * NVOX + (Yb << 6);
#pragma unroll
    for (int i = 0; i < 8; ++i) {
        int j = tid + i * 512;
        int z = j >> 6, x = j & 63;
        pout[(z << 12) + x] = cols[x][z];
    }
}

// ---------------- s-step CG consumers ----------------
// scal: [0]=rr0 [1]=r0.K1 [2]=K1.K1 [3]=r0.K2 [4]=K1.K2

__device__ __forceinline__ float sum8(const float* __restrict__ part, int i) {
    float a = 0.f;
#pragma unroll
    for (int j = 0; j < SPLIT; ++j) a += part[j * NVOX + i];
    return a;
}

// r0 = sum8(part); rr0
__global__ __launch_bounds__(256) void k_r0(const float* __restrict__ part,
                                            float* __restrict__ r0,
                                            float* __restrict__ scal) {
    int i = blockIdx.x * 256 + threadIdx.x;
    float rv = sum8(part, i);
    r0[i] = rv;
    bred256(rv * rv, &scal[0]);
}

// K1 = sum8(part); r0.K1, K1.K1
__global__ __launch_bounds__(256) void k_k1(const float* __restrict__ part,
                                            const float* __restrict__ r0,
                                            float* __restrict__ K1,
                                            float* __restrict__ scal) {
    int i = blockIdx.x * 256 + threadIdx.x;
    float apv = sum8(part, i);
    K1[i] = apv;
    bred2(r0[i] * apv, apv * apv, &scal[1], &scal[2]);
}

// r0.K2, K1.K2   (K2 itself never stored)
__global__ __launch_bounds__(256) void k_dots2(const float* __restrict__ part,
                                               const float* __restrict__ r0,
                                               const float* __restrict__ K1,
                                               float* __restrict__ scal) {
    int i = blockIdx.x * 256 + threadIdx.x;
    float apv = sum8(part, i);
    bred2(r0[i] * apv, K1[i] * apv, &scal[3], &scal[4]);
}

// out = relu(x0 + c1 r0 + c2 K1), coefficients from the 5 scalars
__global__ __launch_bounds__(256) void k_out(const float* __restrict__ x0,
                                             const float* __restrict__ r0,
                                             const float* __restrict__ K1,
                                             const float* __restrict__ scal,
                                             float* __restrict__ out) {
    int i = blockIdx.x * 256 + threadIdx.x;
    float rr0  = scal[0], rK1 = scal[1], K1K1 = scal[2];
    float rK2  = scal[3], K1K2 = scal[4];
    float a0   = rr0 / rK1;                                   // alpha0 (pAp0 = r0.K1)
    float rr1  = rr0 - 2.f * a0 * rK1 + a0 * a0 * K1K1;       // |r1|^2
    float beta = rr1 / rr0;
    float ob   = 1.f + beta;
    // pAp1 = (ob r0 - a0 K1) . (ob K1 - a0 K2)
    float pAp1 = ob * ob * rK1 - ob * a0 * rK2 - a0 * ob * K1K1 + a0 * a0 * K1K2;
    float a1   = rr1 / pAp1;
    float c1   = a0 + a1 * ob;
    float c2   = -a1 * a0;
    float v = fmaf(c2, K1[i], fmaf(c1, r0[i], x0[i]));
    out[i] = v > 0.f ? v : 0.f;
}

extern "C" void kernel_launch(void* const* d_in, const int* in_sizes, int n_in,
                              void* d_out, int out_size, void* d_ws, size_t ws_size,
                              hipStream_t stream) {
    const float* transforms = (const float*)d_in[0];
    const float* slices     = (const float*)d_in[1];
    const float* volume     = (const float*)d_in[2];
    const float* psf        = (const float*)d_in[3];
    float* out = (float*)d_out;

    float* tab    = (float*)d_ws;             // NTAB*16
    float* gbuf   = tab    + NTAB * 16;       // GP_TOT (zero-padded g)
    float* scal   = gbuf   + GP_TOT;          // 8 floats
    float* part   = scal   + 8;               // 8 * NVOX
    float* r0     = part   + SPLIT * NVOX;
    float* K1     = r0     + NVOX;

    const int ablk = 64 * SPLIT;              // 512 (k_atv)
    const int fblk = NPIX / 256;              // 1024 (k_a)
    const int vblk = NVOX / 256;              // 1024

    // one memset covers padded-g borders AND scal
    hipMemsetAsync(gbuf, 0, (GP_TOT + 8) * sizeof(float), stream);
    k_setup<<<(NTAB + 255) / 256, 256, 0, stream>>>(transforms, psf, tab);

    // r0 = At(slices - A(x0)); rr0
    k_a<true><<<fblk, 256, 0, stream>>>(volume, gbuf, transforms, psf, slices);
    k_atv<<<ablk, 512, 0, stream>>>(gbuf, part, tab);
    k_r0<<<vblk, 256, 0, stream>>>(part, r0, scal);

    // K1 = AtA(r0); r0.K1, K1.K1
    k_a<false><<<fblk, 256, 0, stream>>>(r0, gbuf, transforms, psf, nullptr);
    k_atv<<<ablk, 512, 0, stream>>>(gbuf, part, tab);
    k_k1<<<vblk, 256, 0, stream>>>(part, r0, K1, scal);

    // K2 = AtA(K1); r0.K2, K1.K2 (K2 not stored)
    k_a<false><<<fblk, 256, 0, stream>>>(K1, gbuf, transforms, psf, nullptr);
    k_atv<<<ablk, 512, 0, stream>>>(gbuf, part, tab);
    k_dots2<<<vblk, 256, 0, stream>>>(part, r0, K1, scal);

    // out = relu(x0 + c1 r0 + c2 K1)
    k_out<<<vblk, 256, 0, stream>>>(volume, r0, K1, scal, out);
}

// Round 18
// 274.003 us; speedup vs baseline: 1.0733x; 1.0703x over previous
//
#include <hip/hip_runtime.h>

#define NS 64
#define HH 64
#define WW 64
#define VD 64
#define VH 64
#define VW 64
#define NVOX (VD*VH*VW)
#define NPIX (NS*HH*WW)
#define RES 1.5f
#define NTAB (NS*27)
#define WIN 6
#define SPLIT 8
#define COL_PAD 67
#define GP_ROW 68
#define GP_SLC (66*GP_ROW)      // 4488 floats per padded slice
#define GP_TOT (NS*GP_SLC)      // 287232

// ---------------------------------------------------------------
// table entry (16 floats):
//  [0..3]  a,c,b,d   (ws = a*rx + b*ry, hs = c*rx + d*ry)
//  [4..7]  Ux,Uy,Vx,Vy
//  [8..11] Uz,Vz,Cx,Cy
//  [12..15]Cz,psf_k,0,0
// ---------------------------------------------------------------
__device__ __forceinline__ void setup_entry(int i, const float* __restrict__ tr,
                                            const float* __restrict__ psf,
                                            float* __restrict__ tab) {
    int s = i / 27, k = i % 27;
    const float* p = tr + s * 12;
    float R00 = p[0], R01 = p[1], R02 = p[2],  t0 = p[3];
    float R10 = p[4], R11 = p[5], R12 = p[6],  t1 = p[7];
    float R20 = p[8], R21 = p[9], R22 = p[10], t2 = p[11];
    float Ux = RES * R00, Uy = RES * R10, Uz = RES * R20;
    float Vx = RES * R01, Vy = RES * R11, Vz = RES * R21;
    float ox = (float)(k % 3 - 1), oy = (float)((k / 3) % 3 - 1), oz = (float)(k / 9 - 1);
    float Cx = t0 + 31.5f + R00 * ox + R01 * oy + R02 * oz - 31.5f * (Ux + Vx);
    float Cy = t1 + 31.5f + R10 * ox + R11 * oy + R12 * oz - 31.5f * (Uy + Vy);
    float Cz = t2 + 31.5f + R20 * ox + R21 * oy + R22 * oz - 31.5f * (Uz + Vz);
    float inv = 1.f / (Ux * Vy - Uy * Vx);
    float* e = tab + i * 16;
    e[0] = Vy * inv;  e[1] = -Uy * inv;  e[2] = -Vx * inv; e[3] = Ux * inv;
    e[4] = Ux; e[5] = Uy; e[6] = Vx; e[7] = Vy;
    e[8] = Uz; e[9] = Vz; e[10] = Cx; e[11] = Cy;
    e[12] = Cz; e[13] = psf[k]; e[14] = 0.f; e[15] = 0.f;
}

// ---------------------------------------------------------------
// Branch-free trilinear gather (clamped idx, zeroed weights).
// ---------------------------------------------------------------
__device__ __forceinline__ float trilin_gather_bf(const float* __restrict__ vol,
                                                  float px, float py, float pz) {
    float x0 = floorf(px), y0 = floorf(py), z0 = floorf(pz);
    float fx = px - x0, fy = py - y0, fz = pz - z0;
    int ix = (int)x0, iy = (int)y0, iz = (int)z0;

    float wx0 = ((unsigned)ix       < 64u) ? (1.f - fx) : 0.f;
    float wx1 = ((unsigned)(ix + 1) < 64u) ? fx         : 0.f;
    float wy0 = ((unsigned)iy       < 64u) ? (1.f - fy) : 0.f;
    float wy1 = ((unsigned)(iy + 1) < 64u) ? fy         : 0.f;
    float wz0 = ((unsigned)iz       < 64u) ? (1.f - fz) : 0.f;
    float wz1 = ((unsigned)(iz + 1) < 64u) ? fz         : 0.f;

    int xc0 = min(max(ix, 0), 63),     xc1 = min(max(ix + 1, 0), 63);
    int yc0 = min(max(iy, 0), 63) << 6,  yc1 = min(max(iy + 1, 0), 63) << 6;
    int zc0 = min(max(iz, 0), 63) << 12, zc1 = min(max(iz + 1, 0), 63) << 12;

    float v000 = vol[zc0 + yc0 + xc0], v001 = vol[zc0 + yc0 + xc1];
    float v010 = vol[zc0 + yc1 + xc0], v011 = vol[zc0 + yc1 + xc1];
    float v100 = vol[zc1 + yc0 + xc0], v101 = vol[zc1 + yc0 + xc1];
    float v110 = vol[zc1 + yc1 + xc0], v111 = vol[zc1 + yc1 + xc1];

    float w00 = wx0 * wy0, w01 = wx1 * wy0, w10 = wx0 * wy1, w11 = wx1 * wy1;
    float lo = fmaf(w00, v000, fmaf(w01, v001, fmaf(w10, v010, w11 * v011)));
    float hi = fmaf(w00, v100, fmaf(w01, v101, fmaf(w10, v110, w11 * v111)));
    return fmaf(wz0, lo, wz1 * hi);
}

// ---------------------------------------------------------------
// Forward projection body: 1 thread per pixel, per-tap OOB skip.
// Output into ZERO-PADDED g. SUB: g = slc - A(vin).
// ---------------------------------------------------------------
template<bool SUB>
__device__ __forceinline__ void a_body(const float* __restrict__ vin,
                                       float* __restrict__ gp,
                                       const float* __restrict__ tr,
                                       const float* __restrict__ s_psf,
                                       const float* __restrict__ slc,
                                       int gid) {
    int s = gid >> 12;
    int h = (gid >> 6) & 63, w = gid & 63;
    const float* p = tr + s * 12;
    float R0 = p[0], R1 = p[1], R2 = p[2],  t0 = p[3];
    float R3 = p[4], R4 = p[5], R5 = p[6],  t1 = p[7];
    float R6 = p[8], R7 = p[9], R8 = p[10], t2 = p[11];
    float xs = ((float)w - 31.5f) * RES;
    float ys = ((float)h - 31.5f) * RES;
    float p0x = fmaf(R0, xs, fmaf(R1, ys, t0)) + 31.5f;
    float p0y = fmaf(R3, xs, fmaf(R4, ys, t1)) + 31.5f;
    float p0z = fmaf(R6, xs, fmaf(R7, ys, t2)) + 31.5f;
    float a = 0.f;
#pragma unroll
    for (int k = 0; k < 27; ++k) {
        const float ox = (float)(k % 3 - 1), oy = (float)((k / 3) % 3 - 1), oz = (float)(k / 9 - 1);
        float px = p0x + ox * R0 + oy * R1 + oz * R2;
        float py = p0y + ox * R3 + oy * R4 + oz * R5;
        float pz = p0z + ox * R6 + oy * R7 + oz * R8;
        bool inb = (px > -1.f) & (px < 64.f) & (py > -1.f) & (py < 64.f)
                 & (pz > -1.f) & (pz < 64.f);
        if (inb) a = fmaf(s_psf[k], trilin_gather_bf(vin, px, py, pz), a);
    }
    float outv = SUB ? (slc[gid] - a) : a;
    gp[s * GP_SLC + (h + 1) * GP_ROW + (w + 1)] = outv;
}

// plain forward-projection kernel (iters 0/1)
__global__ __launch_bounds__(256) void k_a(const float* __restrict__ vin,
                                           float* __restrict__ gp,
                                           const float* __restrict__ tr,
                                           const float* __restrict__ psf) {
    __shared__ float s_psf[27];
    if (threadIdx.x < 27) s_psf[threadIdx.x] = psf[threadIdx.x];
    __syncthreads();
    a_body<false>(vin, gp, tr, s_psf, nullptr, blockIdx.x * 256 + threadIdx.x);
}

// ---------------------------------------------------------------
// FUSED prologue: blocks [0,1024) = k_a<true> (g = slices - A(x0));
// blocks [1024,1032) = table setup; blocks [1032,1064) = zero gbuf
// borders + scal. All write disjoint memory; deps = inputs only.
// ---------------------------------------------------------------
__global__ __launch_bounds__(256) void k_pre(const float* __restrict__ vin,
                                             float* __restrict__ gp,
                                             const float* __restrict__ tr,
                                             const float* __restrict__ psf,
                                             const float* __restrict__ slc,
                                             float* __restrict__ tab,
                                             float* __restrict__ scal) {
    int b = blockIdx.x;
    if (b < 1024) {
        __shared__ float s_psf[27];
        if (threadIdx.x < 27) s_psf[threadIdx.x] = psf[threadIdx.x];
        __syncthreads();
        a_body<true>(vin, gp, tr, s_psf, slc, b * 256 + threadIdx.x);
    } else if (b < 1032) {
        int i = (b - 1024) * 256 + threadIdx.x;
        if (i < NTAB) setup_entry(i, tr, psf, tab);
    } else {
        int t = (b - 1032) * 256 + threadIdx.x;    // 0..8191
        for (int j = t; j < GP_TOT; j += 32 * 256) {
            int rem = j % GP_SLC;
            int row = rem / GP_ROW;
            int col = rem - row * GP_ROW;
            bool border = (row == 0) | (row == 65) | (col == 0) | (col >= 65);
            if (border) gp[j] = 0.f;
        }
        if (t < 8) scal[t] = 0.f;
    }
}

// ---------------- block reduce helpers (256-thr kernels) ----------------
__device__ __forceinline__ void bred256(float v, float* dst) {
#pragma unroll
    for (int off = 32; off > 0; off >>= 1) v += __shfl_down(v, off, 64);
    __shared__ float s_red[4];
    int lane = threadIdx.x & 63, wid = threadIdx.x >> 6;
    if (lane == 0) s_red[wid] = v;
    __syncthreads();
    if (threadIdx.x == 0) atomicAdd(dst, s_red[0] + s_red[1] + s_red[2] + s_red[3]);
}

__device__ __forceinline__ void bred2(float a, float b, float* da, float* db) {
#pragma unroll
    for (int off = 32; off > 0; off >>= 1) {
        a += __shfl_down(a, off, 64);
        b += __shfl_down(b, off, 64);
    }
    __shared__ float s_red[8];
    int lane = threadIdx.x & 63, wid = threadIdx.x >> 6;
    if (lane == 0) { s_red[wid] = a; s_red[4 + wid] = b; }
    __syncthreads();
    if (threadIdx.x == 0) {
        atomicAdd(da, (s_red[0] + s_red[1]) + (s_red[2] + s_red[3]));
        atomicAdd(db, (s_red[4] + s_red[5]) + (s_red[6] + s_red[7]));
    }
}

// ---------------------------------------------------------------
// Adjoint At (r10-exact): wave-uniform slice -> broadcast table
// loads; 6-slot register z-window; 6-atomic epilogue flush.
// Block = 512 thr = 8 waves; wave = 64 cols (one y-row) x 1 slice.
// blockIdx: Yb = b>>3, split = b&7; slice = split*8 + wave.
// ---------------------------------------------------------------
__global__ __launch_bounds__(512, 2) void k_atv(const float* __restrict__ g,
                                                float* __restrict__ part,
                                                const float* __restrict__ tab) {
    __shared__ float cols[64][COL_PAD];     // 17.2 KB
    int tid = threadIdx.x;
    {
        float4* c4 = (float4*)&cols[0][0];  // 64*67 = 4288 floats = 1072 float4
#pragma unroll
        for (int i = 0; i < 3; ++i) {
            int j = tid + i * 512;
            if (j < 1072) c4[j] = make_float4(0.f, 0.f, 0.f, 0.f);
        }
    }
    __syncthreads();

    int Yb    = blockIdx.x >> 3;
    int split = blockIdx.x & 7;
    int lane  = tid & 63;               // col x
    int wave  = tid >> 6;               // 0..7
    int s = __builtin_amdgcn_readfirstlane(split * 8 + wave);  // wave-uniform
    float X = (float)lane, Y = (float)Yb;

    const float* tb = tab + s * 27 * 16;
    int gbase = s * GP_SLC;

    // window base from center tap (k=13, ox=oy=oz=0)
    const float* ec = tb + 13 * 16;
    float4 ce0 = *(const float4*)(ec);
    float4 ce2 = *(const float4*)(ec + 8);
    float4 ce3 = *(const float4*)(ec + 12);
    float rxc = X - ce2.z, ryc = Y - ce2.w;
    float wsc = ce0.x * rxc + ce0.z * ryc;
    float hsc = ce0.y * rxc + ce0.w * ryc;
    float pzc = fmaf(wsc, ce2.x, fmaf(hsc, ce2.y, ce3.x));
    float basef = floorf(pzc) - 2.f;
    int   basei = (int)basef;

    float acc[WIN];
#pragma unroll
    for (int j = 0; j < WIN; ++j) acc[j] = 0.f;

#pragma unroll 3
    for (int k = 0; k < 27; ++k) {
        const float* e = tb + k * 16;
        float4 e0 = *(const float4*)(e);
        float4 e1 = *(const float4*)(e + 4);
        float4 e2 = *(const float4*)(e + 8);
        float4 e3 = *(const float4*)(e + 12);
        float rx = X - e2.z, ry = Y - e2.w;        // X - Cx, Y - Cy
        float ws = e0.x * rx + e0.z * ry;
        float hs = e0.y * rx + e0.w * ry;
        float w0f = __builtin_amdgcn_fmed3f(floorf(ws), -1.f, 63.f);
        float h0f = __builtin_amdgcn_fmed3f(floorf(hs), -1.f, 63.f);
        int wA = (int)w0f, hA = (int)h0f;
        float Ux = e1.x, Uy = e1.y, Vx = e1.z, Vy = e1.w;
        float Uz = e2.x, Vz = e2.y;
        float Czb = e3.x - basef;
        float psfk = e3.y;
        float Cxr = -rx, Cyr = -ry;                // C - voxel(x,y)
        int colbase = gbase + wA + 1;
#pragma unroll
        for (int dh = 0; dh < 2; ++dh) {
            float fh = h0f + (float)dh;
            float tx  = fmaf(fh, Vx, Cxr);
            float ty  = fmaf(fh, Vy, Cyr);
            float tzb = fmaf(fh, Vz, Czb);
            int rowoff = colbase + (hA + 1 + dh) * GP_ROW;
#pragma unroll
            for (int dw = 0; dw < 2; ++dw) {
                float fw = w0f + (float)dw;
                float ddx = fmaf(fw, Ux, tx);      // px - X
                float ddy = fmaf(fw, Uy, ty);      // py - Y
                float wx = fmaxf(1.f - fabsf(ddx), 0.f);
                float wy = fmaxf(1.f - fabsf(ddy), 0.f);
                float gv = g[rowoff + dw];         // padded: OOB -> 0
                float val = wx * wy * psfk * gv;
                float prel = fmaf(fw, Uz, tzb);    // pz - basef
#pragma unroll
                for (int j = 0; j < WIN; ++j) {
                    float t = fmaxf(0.f, 1.f - fabsf(prel - (float)j));
                    acc[j] = fmaf(val, t, acc[j]);
                }
            }
        }
    }

#pragma unroll
    for (int j = 0; j < WIN; ++j) {
        int zj = basei + j;
        int okz = ((unsigned)zj < 64u);
        int zc = min(max(zj, 0), 63);
        atomicAdd(&cols[lane][zc], okz ? acc[j] : 0.f);
    }
    __syncthreads();

    // write partial: full y-row, 64 cols x 64 z
    float* pout = part + split * NVOX + (Yb << 6);
#pragma unroll
    for (int i = 0; i < 8; ++i) {
        int j = tid + i * 512;
        int z = j >> 6, x = j & 63;
        pout[(z << 12) + x] = cols[x][z];
    }
}

// ---------------- s-step CG consumers ----------------
// scal: [0]=rr0 [1]=r0.K1 [2]=K1.K1 [3]=r0.K2 [4]=K1.K2

__device__ __forceinline__ float sum8(const float* __restrict__ part, int i) {
    float a = 0.f;
#pragma unroll
    for (int j = 0; j < SPLIT; ++j) a += part[j * NVOX + i];
    return a;
}

// r0 = sum8(part); rr0
__global__ __launch_bounds__(256) void k_r0(const float* __restrict__ part,
                                            float* __restrict__ r0,
                                            float* __restrict__ scal) {
    int i = blockIdx.x * 256 + threadIdx.x;
    float rv = sum8(part, i);
    r0[i] = rv;
    bred256(rv * rv, &scal[0]);
}

// K1 = sum8(part); r0.K1, K1.K1
__global__ __launch_bounds__(256) void k_k1(const float* __restrict__ part,
                                            const float* __restrict__ r0,
                                            float* __restrict__ K1,
                                            float* __restrict__ scal) {
    int i = blockIdx.x * 256 + threadIdx.x;
    float apv = sum8(part, i);
    K1[i] = apv;
    bred2(r0[i] * apv, apv * apv, &scal[1], &scal[2]);
}

// r0.K2, K1.K2   (K2 itself never stored)
__global__ __launch_bounds__(256) void k_dots2(const float* __restrict__ part,
                                               const float* __restrict__ r0,
                                               const float* __restrict__ K1,
                                               float* __restrict__ scal) {
    int i = blockIdx.x * 256 + threadIdx.x;
    float apv = sum8(part, i);
    bred2(r0[i] * apv, K1[i] * apv, &scal[3], &scal[4]);
}

// out = relu(x0 + c1 r0 + c2 K1), coefficients from the 5 scalars
__global__ __launch_bounds__(256) void k_out(const float* __restrict__ x0,
                                             const float* __restrict__ r0,
                                             const float* __restrict__ K1,
                                             const float* __restrict__ scal,
                                             float* __restrict__ out) {
    int i = blockIdx.x * 256 + threadIdx.x;
    float rr0  = scal[0], rK1 = scal[1], K1K1 = scal[2];
    float rK2  = scal[3], K1K2 = scal[4];
    float a0   = rr0 / rK1;                                   // alpha0 (pAp0 = r0.K1)
    float rr1  = rr0 - 2.f * a0 * rK1 + a0 * a0 * K1K1;       // |r1|^2
    float beta = rr1 / rr0;
    float ob   = 1.f + beta;
    // pAp1 = (ob r0 - a0 K1) . (ob K1 - a0 K2)
    float pAp1 = ob * ob * rK1 - ob * a0 * rK2 - a0 * ob * K1K1 + a0 * a0 * K1K2;
    float a1   = rr1 / pAp1;
    float c1   = a0 + a1 * ob;
    float c2   = -a1 * a0;
    float v = fmaf(c2, K1[i], fmaf(c1, r0[i], x0[i]));
    out[i] = v > 0.f ? v : 0.f;
}

extern "C" void kernel_launch(void* const* d_in, const int* in_sizes, int n_in,
                              void* d_out, int out_size, void* d_ws, size_t ws_size,
                              hipStream_t stream) {
    const float* transforms = (const float*)d_in[0];
    const float* slices     = (const float*)d_in[1];
    const float* volume     = (const float*)d_in[2];
    const float* psf        = (const float*)d_in[3];
    float* out = (float*)d_out;

    float* tab    = (float*)d_ws;             // NTAB*16
    float* gbuf   = tab    + NTAB * 16;       // GP_TOT (zero-padded g)
    float* scal   = gbuf   + GP_TOT;          // 8 floats
    float* part   = scal   + 8;               // 8 * NVOX
    float* r0     = part   + SPLIT * NVOX;
    float* K1     = r0     + NVOX;

    const int ablk = 64 * SPLIT;              // 512 (k_atv)
    const int fblk = NPIX / 256;              // 1024 (k_a)
    const int vblk = NVOX / 256;              // 1024

    // 1: fused prologue (g = slices - A(x0), table setup, border/scal zero)
    k_pre<<<fblk + 40, 256, 0, stream>>>(volume, gbuf, transforms, psf,
                                         slices, tab, scal);
    // 2-3: r0 = At(g); rr0
    k_atv<<<ablk, 512, 0, stream>>>(gbuf, part, tab);
    k_r0<<<vblk, 256, 0, stream>>>(part, r0, scal);

    // 4-6: K1 = AtA(r0); r0.K1, K1.K1
    k_a<<<fblk, 256, 0, stream>>>(r0, gbuf, transforms, psf);
    k_atv<<<ablk, 512, 0, stream>>>(gbuf, part, tab);
    k_k1<<<vblk, 256, 0, stream>>>(part, r0, K1, scal);

    // 7-9: K2 = AtA(K1); r0.K2, K1.K2 (K2 not stored)
    k_a<<<fblk, 256, 0, stream>>>(K1, gbuf, transforms, psf);
    k_atv<<<ablk, 512, 0, stream>>>(gbuf, part, tab);
    k_dots2<<<vblk, 256, 0, stream>>>(part, r0, K1, scal);

    // 10: out = relu(x0 + c1 r0 + c2 K1)
    k_out<<<vblk, 256, 0, stream>>>(volume, r0, K1, scal, out);
}